// Round 1
// 512.491 us; speedup vs baseline: 1.1320x; 1.1320x over previous
//
#include <hip/hip_runtime.h>
#include <math.h>

#define DD 128
typedef unsigned int   u32;
typedef unsigned short u16;
typedef short bf16x8 __attribute__((ext_vector_type(8)));
typedef float f32x4  __attribute__((ext_vector_type(4)));

__device__ __forceinline__ float lo2f(u32 p){ return __uint_as_float(p << 16); }
__device__ __forceinline__ float hi2f(u32 p){ return __uint_as_float(p & 0xFFFF0000u); }
__device__ __forceinline__ u16 f2bf(float f){
    u32 u = __float_as_uint(f);
    return (u16)((u + 0x7fffu + ((u >> 16) & 1u)) >> 16);   // RNE
}

// ---------------- CSR build ----------------
__global__ void k_hist(const int* __restrict__ dst, int* __restrict__ deg, int E){
    int i = blockIdx.x*256 + threadIdx.x;
    if (i < E) atomicAdd(&deg[dst[i]], 1);
}

__global__ void k_chunksum(const int* __restrict__ deg, int* __restrict__ csum,
                           float* __restrict__ invdeg, int n){
    __shared__ int sdata[256];
    int t = threadIdx.x;
    int i0 = blockIdx.x*512 + t*2;
    int a = (i0     < n) ? deg[i0]   : 0;
    int b = (i0 + 1 < n) ? deg[i0+1] : 0;
    if (i0     < n) invdeg[i0]   = 1.0f / (float)max(a, 1);
    if (i0 + 1 < n) invdeg[i0+1] = 1.0f / (float)max(b, 1);
    sdata[t] = a + b; __syncthreads();
    for (int off = 128; off > 0; off >>= 1){
        if (t < off) sdata[t] += sdata[t+off];
        __syncthreads();
    }
    if (t == 0) csum[blockIdx.x] = sdata[0];
}

// parallel single-block scan over chunk sums (replaces serial loop)
__global__ void k_scanchunks(int* __restrict__ csum, int nchunks,
                             int* __restrict__ row_ptr, int n){
    __shared__ int s[256];
    __shared__ int carry_sh;
    int t = threadIdx.x;
    if (t == 0) carry_sh = 0;
    __syncthreads();
    for (int base = 0; base < nchunks; base += 256){
        int i = base + t;
        int v = (i < nchunks) ? csum[i] : 0;
        s[t] = v;
        __syncthreads();
        for (int off = 1; off < 256; off <<= 1){
            int u = (t >= off) ? s[t-off] : 0;
            __syncthreads();
            s[t] += u;
            __syncthreads();
        }
        int carry = carry_sh;
        int excl  = carry + s[t] - v;
        if (i < nchunks) csum[i] = excl;
        int tot = s[255];
        __syncthreads();
        if (t == 0) carry_sh = carry + tot;
        __syncthreads();
    }
    if (t == 0) row_ptr[n] = carry_sh;
}

__global__ void k_scanwithin(const int* __restrict__ deg, const int* __restrict__ csum,
                             int* __restrict__ row_ptr, int* __restrict__ cursor, int n){
    __shared__ int s[256];
    int t = threadIdx.x;
    int i0 = blockIdx.x*512 + t*2;
    int a = (i0     < n) ? deg[i0]   : 0;
    int b = (i0 + 1 < n) ? deg[i0+1] : 0;
    int tsum = a + b;
    s[t] = tsum; __syncthreads();
    for (int off = 1; off < 256; off <<= 1){
        int v = (t >= off) ? s[t-off] : 0;
        __syncthreads();
        s[t] += v;
        __syncthreads();
    }
    int excl = s[t] - tsum + csum[blockIdx.x];
    if (i0     < n){ row_ptr[i0]   = excl;     cursor[i0]   = excl;     }
    if (i0 + 1 < n){ row_ptr[i0+1] = excl + a; cursor[i0+1] = excl + a; }
}

// cursor pre-seeded with row starts -> no row_ptr add, no cursor memset
__global__ void k_fill(const int* __restrict__ src, const int* __restrict__ dst,
                       int* __restrict__ cursor, int* __restrict__ sorted_src, int E){
    int i = blockIdx.x*256 + threadIdx.x;
    if (i < E){
        int p = atomicAdd(&cursor[dst[i]], 1);
        sorted_src[p] = src[i];
    }
}

// all three W tables in one launch (blockIdx.y selects table)
__global__ void k_w2b3(const float* __restrict__ w0, const float* __restrict__ w1,
                       const float* __restrict__ w2,
                       u16* __restrict__ o0, u16* __restrict__ o1, u16* __restrict__ o2,
                       int nw){
    int i = blockIdx.x*256 + threadIdx.x;
    if (i >= nw) return;
    const float* s = (blockIdx.y == 0) ? w0 : (blockIdx.y == 1) ? w1 : w2;
    u16*         o = (blockIdx.y == 0) ? o0 : (blockIdx.y == 1) ? o1 : o2;
    o[i] = f2bf(s[i]);
}

// ---------------- MFMA GEMM + fused pre/post transforms ----------------
// PRE : 0 none | 1 logmap0 row-scale | 2 l2norm row-scale
// POST: 0 none | 1 l2norm
template<int PRE, int POST>
__device__ __forceinline__ void gemm_body(const float* __restrict__ X, const u16* __restrict__ Wb,
                                          const float* __restrict__ bias, u16* __restrict__ Y,
                                          int n_rows, const float* __restrict__ cptr){
    int t = threadIdx.x;
    int wave = t >> 6, lane = t & 63;
    int q = lane >> 4, m = lane & 15;
    int rowbase = blockIdx.x*64 + wave*16;
    int gr = min(rowbase + m, n_rows - 1);

    float4 xv[8];
    const float4* xp = (const float4*)(X + (size_t)gr*DD);
    #pragma unroll
    for (int c = 0; c < 4; c++){
        xv[2*c]   = xp[c*8 + q*2];
        xv[2*c+1] = xp[c*8 + q*2 + 1];
    }

    float scale = 1.0f;
    if (PRE != 0){
        float ss = 0.f;
        #pragma unroll
        for (int i = 0; i < 8; i++)
            ss += xv[i].x*xv[i].x + xv[i].y*xv[i].y + xv[i].z*xv[i].z + xv[i].w*xv[i].w;
        ss += __shfl_xor(ss, 16, 64);
        ss += __shfl_xor(ss, 32, 64);
        float nrm = sqrtf(ss);
        if (PRE == 1){
            float c  = cptr[0];
            c = (c > 0.f && c < 1e30f) ? c : 1.0f;
            float sc = sqrtf(c);
            float n2 = fmaxf(nrm, 1e-10f);
            float a  = fminf(sc*n2, 0.99999994f);
            scale = (2.0f/sc) * atanhf(a) / n2;
        } else {
            scale = 1.0f / fmaxf(nrm, 1e-12f);
        }
    }

    bf16x8 af[4];
    #pragma unroll
    for (int c = 0; c < 4; c++){
        const float* xf = (const float*)&xv[2*c];
        #pragma unroll
        for (int j = 0; j < 8; j++) af[c][j] = (short)f2bf(xf[j]*scale);
    }

    f32x4 acc[8];
    #pragma unroll
    for (int tl = 0; tl < 8; tl++) acc[tl] = (f32x4){0.f,0.f,0.f,0.f};

    const u16* wb = Wb + (size_t)m*DD + q*8;
    #pragma unroll
    for (int c = 0; c < 4; c++){
        #pragma unroll
        for (int tl = 0; tl < 8; tl++){
            bf16x8 bfr = *(const bf16x8*)(wb + (size_t)tl*16*DD + c*32);
            acc[tl] = __builtin_amdgcn_mfma_f32_16x16x32_bf16(af[c], bfr, acc[tl], 0, 0, 0);
        }
    }

    #pragma unroll
    for (int tl = 0; tl < 8; tl++){
        float bv = bias[tl*16 + m];
        #pragma unroll
        for (int r = 0; r < 4; r++) acc[tl][r] += bv;
    }
    if (POST == 1){
        float ssr[4] = {0.f,0.f,0.f,0.f};
        #pragma unroll
        for (int tl = 0; tl < 8; tl++)
            #pragma unroll
            for (int r = 0; r < 4; r++) ssr[r] += acc[tl][r]*acc[tl][r];
        #pragma unroll
        for (int r = 0; r < 4; r++){
            float s = ssr[r];
            s += __shfl_xor(s, 1, 64);
            s += __shfl_xor(s, 2, 64);
            s += __shfl_xor(s, 4, 64);
            s += __shfl_xor(s, 8, 64);
            float sc = 1.0f / fmaxf(sqrtf(s), 1e-12f);
            #pragma unroll
            for (int tl = 0; tl < 8; tl++) acc[tl][r] *= sc;
        }
    }
    #pragma unroll
    for (int r = 0; r < 4; r++){
        int grow = rowbase + q*4 + r;
        if (grow < n_rows){
            #pragma unroll
            for (int tl = 0; tl < 8; tl++)
                Y[(size_t)grow*DD + tl*16 + m] = f2bf(acc[tl][r]);
        }
    }
}

// all three paths in one launch: y=0 Euclid, y=1 hyperbolic, y=2 spherical
__global__ __launch_bounds__(256, 4)
void k_gemm3(const float* __restrict__ Xe, const float* __restrict__ Xb, const float* __restrict__ Xs,
             const u16* __restrict__ We, const u16* __restrict__ Wh, const u16* __restrict__ Ws,
             const float* __restrict__ be, const float* __restrict__ bb, const float* __restrict__ bs,
             u16* __restrict__ Ye, u16* __restrict__ Yb, u16* __restrict__ Ys,
             int n_rows, const float* __restrict__ cptr){
    if (blockIdx.y == 0)      gemm_body<0,0>(Xe, We, be, Ye, n_rows, cptr);
    else if (blockIdx.y == 1) gemm_body<1,0>(Xb, Wh, bb, Yb, n_rows, cptr);
    else                      gemm_body<2,1>(Xs, Ws, bs, Ys, n_rows, cptr);
}

// ---------------- fused triple mean-aggregate + epilogues ----------------
// Wave per node. Lanes split 4 groups x 16; group g walks edges beg+g, beg+g+4, ...
// Each lane loads dwordx4 (8 bf16 cols) from all 3 h tables at the same offset.
// After xor(16)/xor(32) group-reduce, group 0/1/2 stores e/b/s path.
__device__ __forceinline__ void acc8(float* a, uint4 p){
    a[0] += lo2f(p.x); a[1] += hi2f(p.x);
    a[2] += lo2f(p.y); a[3] += hi2f(p.y);
    a[4] += lo2f(p.z); a[5] += hi2f(p.z);
    a[6] += lo2f(p.w); a[7] += hi2f(p.w);
}

__global__ __launch_bounds__(256)
void k_agg3(const u32* __restrict__ he, const u32* __restrict__ hb, const u32* __restrict__ hs,
            const int* __restrict__ row_ptr, const int* __restrict__ sorted_src,
            const float* __restrict__ invdeg,
            float* __restrict__ out_e, float* __restrict__ out_b, float* __restrict__ out_s,
            int n_rows, const float* __restrict__ cptr){
    int wid = (blockIdx.x*256 + threadIdx.x) >> 6;
    if (wid >= n_rows) return;
    int lane = threadIdx.x & 63;
    int g = lane >> 4, c = lane & 15;
    int beg = row_ptr[wid], end = row_ptr[wid+1];
    int coff = c*4;

    float ae[8], ab[8], as_[8];
    #pragma unroll
    for (int i = 0; i < 8; i++){ ae[i] = 0.f; ab[i] = 0.f; as_[i] = 0.f; }

    int p = beg + g;
    for (; p + 4 < end; p += 8){                 // two edges in flight per group
        size_t o0 = (size_t)sorted_src[p]  *64 + coff;
        size_t o1 = (size_t)sorted_src[p+4]*64 + coff;
        uint4 e0 = *(const uint4*)(he + o0);
        uint4 b0 = *(const uint4*)(hb + o0);
        uint4 s0 = *(const uint4*)(hs + o0);
        uint4 e1 = *(const uint4*)(he + o1);
        uint4 b1 = *(const uint4*)(hb + o1);
        uint4 s1 = *(const uint4*)(hs + o1);
        acc8(ae, e0); acc8(ab, b0); acc8(as_, s0);
        acc8(ae, e1); acc8(ab, b1); acc8(as_, s1);
    }
    if (p < end){                                // at most one remainder per group
        size_t o0 = (size_t)sorted_src[p]*64 + coff;
        uint4 e0 = *(const uint4*)(he + o0);
        uint4 b0 = *(const uint4*)(hb + o0);
        uint4 s0 = *(const uint4*)(hs + o0);
        acc8(ae, e0); acc8(ab, b0); acc8(as_, s0);
    }

    // reduce the 4 edge-groups
    #pragma unroll
    for (int i = 0; i < 8; i++){
        ae[i]  += __shfl_xor(ae[i],  16, 64); ae[i]  += __shfl_xor(ae[i],  32, 64);
        ab[i]  += __shfl_xor(ab[i],  16, 64); ab[i]  += __shfl_xor(ab[i],  32, 64);
        as_[i] += __shfl_xor(as_[i], 16, 64); as_[i] += __shfl_xor(as_[i], 32, 64);
    }
    float inv = invdeg[wid];
    #pragma unroll
    for (int i = 0; i < 8; i++){ ae[i] *= inv; ab[i] *= inv; as_[i] *= inv; }

    // full-row norms for b and s (all groups hold identical values; reduce over c)
    float ssb = 0.f, sss = 0.f;
    #pragma unroll
    for (int i = 0; i < 8; i++){ ssb += ab[i]*ab[i]; sss += as_[i]*as_[i]; }
    #pragma unroll
    for (int msk = 1; msk < 16; msk <<= 1){
        ssb += __shfl_xor(ssb, msk, 64);
        sss += __shfl_xor(sss, msk, 64);
    }

    if (g == 0){
        float o[8];
        #pragma unroll
        for (int i = 0; i < 8; i++) o[i] = ae[i] > 0.f ? ae[i] : 0.2f*ae[i];
        float4* dstp = (float4*)(out_e + (size_t)wid*DD + c*8);
        dstp[0] = make_float4(o[0],o[1],o[2],o[3]);
        dstp[1] = make_float4(o[4],o[5],o[6],o[7]);
    } else if (g == 1){
        float cc = cptr[0];
        cc = (cc > 0.f && cc < 1e30f) ? cc : 1.0f;
        float sc = sqrtf(cc);
        float n2 = fmaxf(sqrtf(ssb), 1e-10f);
        float scale = tanhf(sc*n2*0.5f) / (sc*n2);
        float4* dstp = (float4*)(out_b + (size_t)wid*DD + c*8);
        dstp[0] = make_float4(ab[0]*scale, ab[1]*scale, ab[2]*scale, ab[3]*scale);
        dstp[1] = make_float4(ab[4]*scale, ab[5]*scale, ab[6]*scale, ab[7]*scale);
    } else if (g == 2){
        float scale = 1.0f / fmaxf(sqrtf(sss), 1e-12f);
        float4* dstp = (float4*)(out_s + (size_t)wid*DD + c*8);
        dstp[0] = make_float4(as_[0]*scale, as_[1]*scale, as_[2]*scale, as_[3]*scale);
        dstp[1] = make_float4(as_[4]*scale, as_[5]*scale, as_[6]*scale, as_[7]*scale);
    }
}

extern "C" void kernel_launch(void* const* d_in, const int* in_sizes, int n_in,
                              void* d_out, int out_size, void* d_ws, size_t ws_size,
                              hipStream_t stream){
    const int*   src = (const int*)d_in[0];
    const int*   dst = (const int*)d_in[1];
    const float* emb_in[3] = {(const float*)d_in[2], (const float*)d_in[3], (const float*)d_in[4]};
    const float* W_in[3]   = {(const float*)d_in[5], (const float*)d_in[7], (const float*)d_in[9]};
    const float* b_in[3]   = {(const float*)d_in[6], (const float*)d_in[8], (const float*)d_in[10]};
    const float* b_c       = (const float*)d_in[11];

    const int E  = in_sizes[0];
    const int ND = in_sizes[2];
    const int N  = ND / DD;
    const int Lnum = in_sizes[5] / (DD*DD);
    const int nw = Lnum*DD*DD;
    const int nchunks = (N + 511) / 512;

    char* w = (char*)d_ws;
    auto alloc = [&](size_t bytes)->char*{
        char* p = w; w += (bytes + 255) & ~(size_t)255; return p;
    };
    u32*   hE        = (u32*)  alloc((size_t)ND*2);     // bf16 h tables (one per path)
    u32*   hB        = (u32*)  alloc((size_t)ND*2);
    u32*   hS        = (u32*)  alloc((size_t)ND*2);
    u16*   Wb[3];
    for (int i = 0; i < 3; i++) Wb[i] = (u16*)alloc((size_t)nw*2);
    float* invdeg    = (float*)alloc((size_t)N*4);
    int*   deg       = (int*)  alloc((size_t)N*4);
    int*   row_ptr   = (int*)  alloc((size_t)(N+1)*4);
    int*   cursor    = (int*)  alloc((size_t)N*4);
    int*   csum      = (int*)  alloc((size_t)nchunks*4);
    int*   sorted_src= (int*)  alloc((size_t)E*4);
    (void)ws_size; (void)n_in; (void)out_size;

    float* out_e = (float*)d_out;
    float* out_b = out_e + ND;
    float* out_s = out_e + 2*ND;

    hipMemsetAsync(deg, 0, (size_t)N*4, stream);

    const int TB = 256;
    k_w2b3<<<dim3((nw+TB-1)/TB, 3), TB, 0, stream>>>(W_in[0], W_in[1], W_in[2],
                                                     Wb[0], Wb[1], Wb[2], nw);
    k_hist<<<(E+TB-1)/TB, TB, 0, stream>>>(dst, deg, E);
    k_chunksum<<<nchunks, 256, 0, stream>>>(deg, csum, invdeg, N);
    k_scanchunks<<<1, 256, 0, stream>>>(csum, nchunks, row_ptr, N);
    k_scanwithin<<<nchunks, 256, 0, stream>>>(deg, csum, row_ptr, cursor, N);
    k_fill<<<(E+TB-1)/TB, TB, 0, stream>>>(src, dst, cursor, sorted_src, E);

    const int rowblocks  = (N + 3) / 4;
    const int gemmblocks = (N + 63) / 64;

    const float* se = emb_in[0];
    const float* sb = emb_in[1];
    const float* ss = emb_in[2];

    for (int l = 0; l < Lnum; l++){
        k_gemm3<<<dim3(gemmblocks, 3), 256, 0, stream>>>(
            se, sb, ss,
            Wb[0] + (size_t)l*DD*DD, Wb[1] + (size_t)l*DD*DD, Wb[2] + (size_t)l*DD*DD,
            b_in[0] + (size_t)l*DD,  b_in[1] + (size_t)l*DD,  b_in[2] + (size_t)l*DD,
            (u16*)hE, (u16*)hB, (u16*)hS, N, b_c);
        k_agg3<<<rowblocks, 256, 0, stream>>>(hE, hB, hS, row_ptr, sorted_src, invdeg,
                                              out_e, out_b, out_s, N, b_c);
        se = out_e; sb = out_b; ss = out_s;
    }
}